// Round 17
// baseline (67.443 us; speedup 1.0000x reference)
//
#include <hip/hip_runtime.h>
#include <hip/hip_fp16.h>

#define DIN 256
#define DOUT 128
#define KNBR 32
#define MT 128        // M-tile rows per FC block; grid 391

typedef __attribute__((ext_vector_type(4))) float f32x4;
typedef __attribute__((ext_vector_type(8))) short bf16x8;

// packed f32x2 -> bf16x2 (RNE); no builtin on gfx950 -> inline asm
static __device__ __forceinline__ uint cvtpk(float lo, float hi) {
    uint r;
    asm("v_cvt_pk_bf16_f32 %0, %1, %2" : "=v"(r) : "v"(lo), "v"(hi));
    return r;
}

static __device__ __forceinline__ bf16x8 cvt8(const f32x4 lo, const f32x4 hi) {
    uint4 u;
    u.x = cvtpk(lo.x, lo.y); u.y = cvtpk(lo.z, lo.w);
    u.z = cvtpk(hi.x, hi.y); u.w = cvtpk(hi.z, hi.w);
    union { uint4 q; bf16x8 v; } cv; cv.q = u;
    return cv.v;
}

// h[n][o] = relu(feats[n][:].W[o][:] + b[o]) via bf16 MFMA.
// h stored as FOUR fp16 column-planes [4][N][32] (3.2 MB each -> per-XCD
// L2-resident for the pool). fc itself is fabric-bound (~27 us); keeper
// structure: reg-staged A, swizzled LDS, pure ds_read+MFMA, W fp32 direct.
__global__ __launch_bounds__(256) void fc_mfma_kernel(
    const float* __restrict__ feats, const float* __restrict__ W,
    const float* __restrict__ bias, __half* __restrict__ h, int N)
{
    __shared__ char lds[MT * DIN * 2];   // 64 KB: bf16 A-tile, then out-tile
    const int tid  = threadIdx.x;
    const int lane = tid & 63;
    const int wv   = tid >> 6;
    const int wm   = wv >> 1, wn = wv & 1;
    const int l15  = lane & 15, lq = lane >> 4;
    const int nb   = blockIdx.x * MT;

    // ---- stage A: 128 rows x 32 units (16B bf16 = 8 cols); 16 units/thread ----
    #pragma unroll
    for (int i = 0; i < 16; ++i) {
        const int u    = i * 256 + tid;
        const int row  = u >> 5;
        const int unit = u & 31;
        int grow = nb + row; if (grow > N - 1) grow = N - 1;
        const float* src = feats + (size_t)grow * DIN + unit * 8;
        const f32x4 lo = *(const f32x4*)(src);
        const f32x4 hi = *(const f32x4*)(src + 4);
        *(bf16x8*)(lds + row * 512 + (unit ^ (row & 7)) * 16) = cvt8(lo, hi);
    }
    __syncthreads();

    // ---- K loop: pure ds_read + MFMA; B from L2-resident fp32 W (cvt in reg) ----
    f32x4 acc[4][4];
    #pragma unroll
    for (int mi = 0; mi < 4; ++mi)
        #pragma unroll
        for (int ni = 0; ni < 4; ++ni) acc[mi][ni] = (f32x4){0.f, 0.f, 0.f, 0.f};

    #pragma unroll
    for (int ks = 0; ks < 8; ++ks) {
        bf16x8 breg[4];
        #pragma unroll
        for (int ni = 0; ni < 4; ++ni) {
            const float* wr = W + (size_t)(wn * 64 + ni * 16 + l15) * DIN
                                + ks * 32 + lq * 8;
            breg[ni] = cvt8(*(const f32x4*)wr, *(const f32x4*)(wr + 4));
        }
        bf16x8 a[4];
        #pragma unroll
        for (int mi = 0; mi < 4; ++mi) {
            const int row = wm * 64 + mi * 16 + l15;
            a[mi] = *(const bf16x8*)(
                lds + row * 512 + ((ks * 4 + lq) ^ (row & 7)) * 16);
        }
        #pragma unroll
        for (int mi = 0; mi < 4; ++mi)
            #pragma unroll
            for (int ni = 0; ni < 4; ++ni)
                acc[mi][ni] = __builtin_amdgcn_mfma_f32_16x16x32_bf16(
                    a[mi], breg[ni], acc[mi][ni], 0, 0, 0);
    }

    // ---- epilogue: bias+relu -> fp16 out-tile in LDS -> coalesced plane stores ----
    float bcol[4];
    #pragma unroll
    for (int ni = 0; ni < 4; ++ni) bcol[ni] = bias[wn * 64 + ni * 16 + l15];

    __syncthreads();   // A-tile reads done; reuse LDS for out-tile (32 KB)
    #pragma unroll
    for (int mi = 0; mi < 4; ++mi) {
        const int lrow0 = wm * 64 + mi * 16 + lq * 4;
        #pragma unroll
        for (int ni = 0; ni < 4; ++ni) {
            const int col = wn * 64 + ni * 16 + l15;
            #pragma unroll
            for (int r = 0; r < 4; ++r) {
                const float v = fmaxf(acc[mi][ni][r] + bcol[ni], 0.f);
                *(ushort*)(lds + (lrow0 + r) * 256 + col * 2) =
                    __half_as_ushort(__float2half_rn(v));
            }
        }
    }
    __syncthreads();

    // read back: thread t -> row t>>1, planes (t&1)*2 and (t&1)*2+1; 64 B each
    {
        const int lrow = tid >> 1;
        const int ph   = (tid & 1) * 2;
        const int grow = nb + lrow;
        if (grow < N) {
            #pragma unroll
            for (int pp = 0; pp < 2; ++pp) {
                ushort* dst = (ushort*)h + (size_t)(ph + pp) * N * 32
                                        + (size_t)grow * 32;
                #pragma unroll
                for (int i = 0; i < 4; ++i)
                    *(bf16x8*)(dst + i * 8) =
                        *(const bf16x8*)(lds + lrow * 256 + (ph + pp) * 64 + i * 16);
            }
        }
    }
}

// pooled[n][p*32..+31] = mean_k hplane_p[edge[n][k]][:]
// 4 contiguous planes of 3.2 MB, plane = (blockIdx&7)>>1 -> 2 XCDs per plane,
// per-XCD gather working set 3.2 MB < 4 MB L2 -> resident after compulsory
// fill; gathers run at L2 rate. Contiguous planes mean each 128 B L2 line
// holds 2 same-plane rows (no cross-plane waste -- the r7 failure mode).
// 64 nodes/block, 4 lanes/node x 16 B = 64 B row-slice. eLds stride 33
// (padding: stride-32 layout put every node-group on the same bank).
struct __align__(16) Half8 { __half2 a, b, c, d; };

__global__ __launch_bounds__(256) void pool_kernel(
    const __half* __restrict__ h, const int* __restrict__ edge,
    float* __restrict__ out, int N, int nchunks)
{
    const int bi    = blockIdx.x;
    const int p     = (bi & 7) >> 1;                 // plane 0..3, fixed per XCD
    const int chunk = ((bi >> 3) << 1) | (bi & 1);   // chunk within plane
    if (chunk >= nchunks) return;                    // block-uniform guard
    const int nb = chunk * 64;

    __shared__ int eLds[64 * 33];              // 8.25 KB, padded stride
    const int tid = threadIdx.x;

    // stage this chunk's 2048 edge indices (coalesced, guarded)
    const int* esrc = edge + (size_t)nb * KNBR;
    const int limit = (N - nb) * KNBR;
    #pragma unroll
    for (int i = 0; i < 8; ++i) {
        const int ei = tid + i * 256;
        eLds[(ei >> 5) * 33 + (ei & 31)] = (ei < limit) ? esrc[ei] : 0;
    }
    __syncthreads();

    const int g = tid >> 2;                    // local node 0..63
    const int l = tid & 3;                     // 4 lanes x 16 B = 64 B slice
    const int node = nb + g;
    if (node >= N) return;

    const Half8* plane = (const Half8*)((const ushort*)h + (size_t)p * N * 32);
    const int* el = &eLds[g * 33];             // plane row = 4 Half8 = 64 B

    float4 acc0 = {0.f, 0.f, 0.f, 0.f};
    float4 acc1 = {0.f, 0.f, 0.f, 0.f};

    #pragma unroll
    for (int b = 0; b < 2; ++b) {
        Half8 v[16];
        #pragma unroll
        for (int k = 0; k < 16; ++k)
            v[k] = plane[(size_t)el[b * 16 + k] * 4 + l];
        #pragma unroll
        for (int k = 0; k < 16; ++k) {
            const float2 f0 = __half22float2(v[k].a);
            const float2 f1 = __half22float2(v[k].b);
            const float2 f2 = __half22float2(v[k].c);
            const float2 f3 = __half22float2(v[k].d);
            acc0.x += f0.x; acc0.y += f0.y; acc0.z += f1.x; acc0.w += f1.y;
            acc1.x += f2.x; acc1.y += f2.y; acc1.z += f3.x; acc1.w += f3.y;
        }
    }

    const float s = 1.0f / (float)KNBR;
    float4 r0, r1;
    r0.x = acc0.x * s; r0.y = acc0.y * s; r0.z = acc0.z * s; r0.w = acc0.w * s;
    r1.x = acc1.x * s; r1.y = acc1.y * s; r1.z = acc1.z * s; r1.w = acc1.w * s;

    float4* op = (float4*)(out + (size_t)node * DOUT + p * 32 + l * 8);
    op[0] = r0; op[1] = r1;
}

extern "C" void kernel_launch(void* const* d_in, const int* in_sizes, int n_in,
                              void* d_out, int out_size, void* d_ws, size_t ws_size,
                              hipStream_t stream) {
    // dict order: ids, feats, W, b, edge_dict, G, ite
    const float* feats = (const float*)d_in[1];
    const float* W     = (const float*)d_in[2];
    const float* bias  = (const float*)d_in[3];
    const int*   edge  = (const int*)d_in[4];
    float* out = (float*)d_out;

    const int N = in_sizes[1] / DIN;            // 50000
    __half* h   = (__half*)d_ws;                // 4 planes x N x 32 fp16 = 12.8 MB

    fc_mfma_kernel<<<(N + MT - 1) / MT, 256, 0, stream>>>(feats, W, bias, h, N);

    const int nchunks = (N + 63) / 64;          // 782 chunks per plane
    const int grid = ((nchunks + 1) / 2) * 8;   // 3128: (chunk,plane) bijective
    pool_kernel<<<grid, 256, 0, stream>>>(h, edge, out, N, nchunks);
}

// Round 18
// 61.795 us; speedup vs baseline: 1.0914x; 1.0914x over previous
//
#include <hip/hip_runtime.h>
#include <hip/hip_fp16.h>

#define DIN 256
#define DOUT 128
#define KNBR 32
#define MT 128        // M-tile rows per FC block; grid 391

typedef __attribute__((ext_vector_type(4))) float f32x4;
typedef __attribute__((ext_vector_type(8))) short bf16x8;

// packed f32x2 -> bf16x2 (RNE); no builtin on gfx950 -> inline asm
static __device__ __forceinline__ uint cvtpk(float lo, float hi) {
    uint r;
    asm("v_cvt_pk_bf16_f32 %0, %1, %2" : "=v"(r) : "v"(lo), "v"(hi));
    return r;
}

static __device__ __forceinline__ bf16x8 cvt8(const f32x4 lo, const f32x4 hi) {
    uint4 u;
    u.x = cvtpk(lo.x, lo.y); u.y = cvtpk(lo.z, lo.w);
    u.z = cvtpk(hi.x, hi.y); u.w = cvtpk(hi.z, hi.w);
    union { uint4 q; bf16x8 v; } cv; cv.q = u;
    return cv.v;
}

// h[n][o] = relu(feats[n][:].W[o][:] + b[o]) via bf16 MFMA.
// h stored as two fp16 column-planes [2][N][64]. fc is fabric-bound (~27 us;
// ten structures within noise); keeper: reg-staged A, swizzled LDS, pure
// ds_read+MFMA K loop, W fp32 direct, out-tile staged in LDS.
__global__ __launch_bounds__(256) void fc_mfma_kernel(
    const float* __restrict__ feats, const float* __restrict__ W,
    const float* __restrict__ bias, __half* __restrict__ h, int N)
{
    __shared__ char lds[MT * DIN * 2];   // 64 KB: bf16 A-tile, then out-tile
    const int tid  = threadIdx.x;
    const int lane = tid & 63;
    const int wv   = tid >> 6;
    const int wm   = wv >> 1, wn = wv & 1;
    const int l15  = lane & 15, lq = lane >> 4;
    const int nb   = blockIdx.x * MT;

    // ---- stage A: 128 rows x 32 units (16B bf16 = 8 cols); 16 units/thread ----
    #pragma unroll
    for (int i = 0; i < 16; ++i) {
        const int u    = i * 256 + tid;
        const int row  = u >> 5;
        const int unit = u & 31;
        int grow = nb + row; if (grow > N - 1) grow = N - 1;
        const float* src = feats + (size_t)grow * DIN + unit * 8;
        const f32x4 lo = *(const f32x4*)(src);
        const f32x4 hi = *(const f32x4*)(src + 4);
        *(bf16x8*)(lds + row * 512 + (unit ^ (row & 7)) * 16) = cvt8(lo, hi);
    }
    __syncthreads();

    // ---- K loop: pure ds_read + MFMA; B from L2-resident fp32 W (cvt in reg) ----
    f32x4 acc[4][4];
    #pragma unroll
    for (int mi = 0; mi < 4; ++mi)
        #pragma unroll
        for (int ni = 0; ni < 4; ++ni) acc[mi][ni] = (f32x4){0.f, 0.f, 0.f, 0.f};

    #pragma unroll
    for (int ks = 0; ks < 8; ++ks) {
        bf16x8 breg[4];
        #pragma unroll
        for (int ni = 0; ni < 4; ++ni) {
            const float* wr = W + (size_t)(wn * 64 + ni * 16 + l15) * DIN
                                + ks * 32 + lq * 8;
            breg[ni] = cvt8(*(const f32x4*)wr, *(const f32x4*)(wr + 4));
        }
        bf16x8 a[4];
        #pragma unroll
        for (int mi = 0; mi < 4; ++mi) {
            const int row = wm * 64 + mi * 16 + l15;
            a[mi] = *(const bf16x8*)(
                lds + row * 512 + ((ks * 4 + lq) ^ (row & 7)) * 16);
        }
        #pragma unroll
        for (int mi = 0; mi < 4; ++mi)
            #pragma unroll
            for (int ni = 0; ni < 4; ++ni)
                acc[mi][ni] = __builtin_amdgcn_mfma_f32_16x16x32_bf16(
                    a[mi], breg[ni], acc[mi][ni], 0, 0, 0);
    }

    // ---- epilogue: bias+relu -> fp16 out-tile in LDS (16B-unit XOR swizzle) ----
    float bcol[4];
    #pragma unroll
    for (int ni = 0; ni < 4; ++ni) bcol[ni] = bias[wn * 64 + ni * 16 + l15];

    __syncthreads();   // A-tile reads done; reuse LDS for out-tile (32 KB)
    #pragma unroll
    for (int mi = 0; mi < 4; ++mi) {
        const int lrow0 = wm * 64 + mi * 16 + lq * 4;
        #pragma unroll
        for (int ni = 0; ni < 4; ++ni) {
            const int col = wn * 64 + ni * 16 + l15;
            #pragma unroll
            for (int r = 0; r < 4; ++r) {
                const int lrow = lrow0 + r;
                const float v = fmaxf(acc[mi][ni][r] + bcol[ni], 0.f);
                // unit = col>>3 (0..15) swizzled by row for conflict-free readback
                const int u = ((col >> 3) ^ (lrow & 7));
                *(ushort*)(lds + lrow * 256 + u * 16 + (col & 7) * 2) =
                    __half_as_ushort(__float2half_rn(v));
            }
        }
    }
    __syncthreads();

    // readback: per wave-instruction 8 rows x 128 B = 1 KB contiguous (full
    // lines). tid>>7 = plane, (tid&127)>>3 = row sub-group, tid&7 = 16B seg.
    {
        const int p   = tid >> 7;
        const int idx = tid & 127;
        const int rg  = idx >> 3;
        const int seg = idx & 7;
        #pragma unroll
        for (int r = 0; r < 8; ++r) {
            const int lrow = r * 16 + rg;
            const int grow = nb + lrow;
            if (grow < N) {
                const int u = (p * 8 + seg) ^ (lrow & 7);   // inverse swizzle
                ushort* dst = (ushort*)h + (size_t)p * N * 64
                                        + (size_t)grow * 64 + seg * 8;
                *(bf16x8*)dst = *(const bf16x8*)(lds + lrow * 256 + u * 16);
            }
        }
    }
}

// pooled[n][p*64..+63] = mean_k hplane_p[edge[n][k]][:]
// SINGLE launch, XCD-pinned planes: plane = (blockIdx&7)>>2 -> XCDs 0-3 plane
// 0, XCDs 4-7 plane 1 (proven -5 us in r16). 8 lanes/node x 16 B = 128 B =
// one full L2 line per gathered row (minimum transaction count; r17 proved
// halving the row slice doubles transactions and loses more than residency
// gains). eLds stride padded to 33: stride-32 put all 8 node-groups of a
// wave on bank k -> 8-way conflict per edge read (r7's 800K counter).
struct __align__(16) Half8 { __half2 a, b, c, d; };

__global__ __launch_bounds__(256) void pool_kernel(
    const __half* __restrict__ h, const int* __restrict__ edge,
    float* __restrict__ out, int N, int nchunks)
{
    const int bi    = blockIdx.x;
    const int p     = (bi & 7) >> 2;                 // plane, fixed per XCD
    const int chunk = ((bi >> 3) << 2) | (bi & 3);   // chunk within plane
    if (chunk >= nchunks) return;                    // block-uniform guard
    const int nb = chunk * 32;

    __shared__ int eLds[32 * 33];              // padded stride
    const int tid = threadIdx.x;

    // stage this chunk's 1024 edge indices (coalesced, guarded)
    const int* esrc = edge + (size_t)nb * KNBR;
    const int limit = (N - nb) * KNBR;
    #pragma unroll
    for (int i = 0; i < 4; ++i) {
        const int ei = tid + i * 256;
        eLds[(ei >> 5) * 33 + (ei & 31)] = (ei < limit) ? esrc[ei] : 0;
    }
    __syncthreads();

    const int g = tid >> 3;                    // local node 0..31
    const int l = tid & 7;
    const int node = nb + g;
    if (node >= N) return;

    const Half8* plane = (const Half8*)((const ushort*)h + (size_t)p * N * 64);
    const int* el = &eLds[g * 33];             // plane row = 8 Half8 = 128 B

    float4 acc0 = {0.f, 0.f, 0.f, 0.f};
    float4 acc1 = {0.f, 0.f, 0.f, 0.f};

    #pragma unroll
    for (int b = 0; b < 2; ++b) {
        Half8 v[16];
        #pragma unroll
        for (int k = 0; k < 16; ++k)
            v[k] = plane[(size_t)el[b * 16 + k] * 8 + l];
        #pragma unroll
        for (int k = 0; k < 16; ++k) {
            const float2 f0 = __half22float2(v[k].a);
            const float2 f1 = __half22float2(v[k].b);
            const float2 f2 = __half22float2(v[k].c);
            const float2 f3 = __half22float2(v[k].d);
            acc0.x += f0.x; acc0.y += f0.y; acc0.z += f1.x; acc0.w += f1.y;
            acc1.x += f2.x; acc1.y += f2.y; acc1.z += f3.x; acc1.w += f3.y;
        }
    }

    const float s = 1.0f / (float)KNBR;
    float4 r0, r1;
    r0.x = acc0.x * s; r0.y = acc0.y * s; r0.z = acc0.z * s; r0.w = acc0.w * s;
    r1.x = acc1.x * s; r1.y = acc1.y * s; r1.z = acc1.z * s; r1.w = acc1.w * s;

    float4* op = (float4*)(out + (size_t)node * DOUT + p * 64 + l * 8);
    op[0] = r0; op[1] = r1;
}

extern "C" void kernel_launch(void* const* d_in, const int* in_sizes, int n_in,
                              void* d_out, int out_size, void* d_ws, size_t ws_size,
                              hipStream_t stream) {
    // dict order: ids, feats, W, b, edge_dict, G, ite
    const float* feats = (const float*)d_in[1];
    const float* W     = (const float*)d_in[2];
    const float* bias  = (const float*)d_in[3];
    const int*   edge  = (const int*)d_in[4];
    float* out = (float*)d_out;

    const int N = in_sizes[1] / DIN;            // 50000
    __half* h   = (__half*)d_ws;                // 2 planes x N x 64 fp16 = 12.8 MB

    fc_mfma_kernel<<<(N + MT - 1) / MT, 256, 0, stream>>>(feats, W, bias, h, N);

    const int nchunks = (N + 31) / 32;          // 1563 chunks per plane
    const int grid = ((nchunks + 3) / 4) * 8;   // 3128, (chunk,plane) covered
    pool_kernel<<<grid, 256, 0, stream>>>(h, edge, out, N, nchunks);
}